// Round 4
// baseline (53.093 us; speedup 1.0000x reference)
//
#include <hip/hip_runtime.h>

#define UNITS 4096
#define BATCH 8192

// out[b,j] = x[b,j] * w[j,j]  (masked_w = w * I collapses to a column scale).
//
//  - STRIDE/ITERS compile-time: trip count exactly 16, fully unrolled, so
//    the compiler issues many independent 16B loads in flight (round-2
//    version: VGPR=8, one load in flight, latency-bound at 2.3 TB/s).
//  - Nontemporal stores: `out` is write-once, never re-read; nt keeps it
//    from evicting x (128 MiB) out of the 256 MiB L3 (FETCH_SIZE already
//    showed ~50% of x L3-resident across replays).
//  - vf4 = clang native vector type: __builtin_nontemporal_store rejects
//    HIP_vector_type float4.
typedef float vf4 __attribute__((ext_vector_type(4)));

constexpr int TPB    = 256;
constexpr int NBLK   = 2048;
constexpr int STRIDE = TPB * NBLK;            // 524288 float4s = 512 rows
constexpr int N4     = BATCH * UNITS / 4;     // 8,388,608 float4s
constexpr int ITERS  = N4 / STRIDE;           // 16, exact (no remainder)

__global__ void __launch_bounds__(TPB)
diag_scale_kernel(const float* __restrict__ x,
                  const float* __restrict__ w,
                  float* __restrict__ out) {
    const vf4* __restrict__ x4 = (const vf4*)x;
    vf4* __restrict__ o4 = (vf4*)out;

    const int i0 = blockIdx.x * TPB + threadIdx.x;
    const int c  = i0 & (UNITS / 4 - 1);      // column group, loop-invariant

    // diag[j] = w[j*(UNITS+1)]; 4 scalars per thread, L2-broadcast lines.
    const size_t j0 = (size_t)(4 * c) * (UNITS + 1);
    vf4 dv;
    dv.x = w[j0];
    dv.y = w[j0 + (UNITS + 1)];
    dv.z = w[j0 + 2 * (UNITS + 1)];
    dv.w = w[j0 + 3 * (UNITS + 1)];

#pragma unroll
    for (int k = 0; k < ITERS; ++k) {
        const int i = i0 + k * STRIDE;        // always < N4 (exact division)
        vf4 xv = x4[i];
        vf4 ov = xv * dv;
        __builtin_nontemporal_store(ov, &o4[i]);
    }
}

extern "C" void kernel_launch(void* const* d_in, const int* in_sizes, int n_in,
                              void* d_out, int out_size, void* d_ws, size_t ws_size,
                              hipStream_t stream) {
    const float* x = (const float*)d_in[0];
    const float* w = (const float*)d_in[1];
    float* out = (float*)d_out;

    diag_scale_kernel<<<NBLK, TPB, 0, stream>>>(x, w, out);
}

// Round 5
// 50.328 us; speedup vs baseline: 1.0549x; 1.0549x over previous
//
#include <hip/hip_runtime.h>

#define UNITS 4096
#define BATCH 8192

// out[b,j] = x[b,j] * w[j,j]  (masked_w = w * I collapses to a column scale).
//
// Round-5 structure: two-phase register staging. Phase 1 issues ALL 8
// float4 loads (statically-indexed array -> stays in VGPRs); phase 2
// multiplies and nt-stores in the same order, so the compiler waits
// vmcnt(7)..vmcnt(0) incrementally while stores stream out. Round-4's
// interleaved loop got scheduled with only ~4 loads in flight (VGPR=32,
// VALUBusy 1.5%, 3.9 TB/s effective).
typedef float vf4 __attribute__((ext_vector_type(4)));

constexpr int TPB    = 256;
constexpr int NBLK   = 4096;                  // 2x TLP vs round 4
constexpr int STRIDE = TPB * NBLK;            // 1,048,576 float4s = 1024 rows
constexpr int N4     = BATCH * UNITS / 4;     // 8,388,608 float4s
constexpr int ITERS  = N4 / STRIDE;           // 8, exact

__global__ void __launch_bounds__(TPB)
diag_scale_kernel(const float* __restrict__ x,
                  const float* __restrict__ w,
                  float* __restrict__ out) {
    const vf4* __restrict__ x4 = (const vf4*)x;
    vf4* __restrict__ o4 = (vf4*)out;

    const int i0 = blockIdx.x * TPB + threadIdx.x;
    const int c  = i0 & (UNITS / 4 - 1);      // column group, loop-invariant

    // diag[j] = w[j*(UNITS+1)]; 4 strided scalars, L2-resident after the
    // first blocks touch them (4096 lines, 256 KB total).
    const size_t j0 = (size_t)(4 * c) * (UNITS + 1);
    vf4 dv;
    dv.x = w[j0];
    dv.y = w[j0 + (UNITS + 1)];
    dv.z = w[j0 + 2 * (UNITS + 1)];
    dv.w = w[j0 + 3 * (UNITS + 1)];

    // Phase 1: issue all loads (static indices -> registers, 8 in flight).
    vf4 xs[ITERS];
#pragma unroll
    for (int k = 0; k < ITERS; ++k) {
        xs[k] = x4[i0 + k * STRIDE];
    }

    // Phase 2: consume in issue order; nt stores keep `out` from evicting
    // x's 128 MiB out of the 256 MiB L3 across timed replays.
#pragma unroll
    for (int k = 0; k < ITERS; ++k) {
        vf4 ov = xs[k] * dv;
        __builtin_nontemporal_store(ov, &o4[i0 + k * STRIDE]);
    }
}

extern "C" void kernel_launch(void* const* d_in, const int* in_sizes, int n_in,
                              void* d_out, int out_size, void* d_ws, size_t ws_size,
                              hipStream_t stream) {
    const float* x = (const float*)d_in[0];
    const float* w = (const float*)d_in[1];
    float* out = (float*)d_out;

    diag_scale_kernel<<<NBLK, TPB, 0, stream>>>(x, w, out);
}

// Round 6
// 46.918 us; speedup vs baseline: 1.1316x; 1.0727x over previous
//
#include <hip/hip_runtime.h>

#define UNITS 4096
#define BATCH 8192

// out[b,j] = x[b,j] * w[j,j]  (masked_w = w * I collapses to a column scale).
//
// Round-6 structure: exact m13 copy-ubench shape — one float4 per thread,
// 32768 blocks x 256, no loop (all loop variants pinned at ~50 us / 4 TB/s).
// Diagonal is compacted once into d_ws (16 KB) by a tiny preamble kernel, so
// the hot kernel's scale read is ONE coalesced float4 from an L1-resident
// table (prev rounds: 4 strided 16KB-apart gathers per thread = 4M extra L2
// transactions device-wide).
typedef float vf4 __attribute__((ext_vector_type(4)));

constexpr int TPB  = 256;
constexpr int N4   = BATCH * UNITS / 4;       // 8,388,608 float4s
constexpr int NBLK = N4 / TPB;                // 32768 blocks, exact

__global__ void extract_diag_kernel(const float* __restrict__ w,
                                    float* __restrict__ diag) {
    int j = blockIdx.x * blockDim.x + threadIdx.x;
    if (j < UNITS) {
        diag[j] = w[(size_t)j * (UNITS + 1)];
    }
}

__global__ void __launch_bounds__(TPB)
diag_scale_kernel(const float* __restrict__ x,
                  const float* __restrict__ diag,
                  float* __restrict__ out) {
    const vf4* __restrict__ x4 = (const vf4*)x;
    const vf4* __restrict__ d4 = (const vf4*)diag;
    vf4* __restrict__ o4 = (vf4*)out;

    const int i = blockIdx.x * TPB + threadIdx.x;   // one float4 per thread
    const int c = i & (UNITS / 4 - 1);              // column group

    vf4 dv = d4[c];                                 // 16 KB table: L1-hit
    vf4 xv = x4[i];                                 // HBM/L3 stream
    vf4 ov = xv * dv;
    // nt: out is write-once; keep it from evicting x's L3 residency.
    __builtin_nontemporal_store(ov, &o4[i]);
}

extern "C" void kernel_launch(void* const* d_in, const int* in_sizes, int n_in,
                              void* d_out, int out_size, void* d_ws, size_t ws_size,
                              hipStream_t stream) {
    const float* x = (const float*)d_in[0];
    const float* w = (const float*)d_in[1];
    float* out = (float*)d_out;
    float* diag = (float*)d_ws;                     // 16 KB scratch

    extract_diag_kernel<<<(UNITS + TPB - 1) / TPB, TPB, 0, stream>>>(w, diag);
    diag_scale_kernel<<<NBLK, TPB, 0, stream>>>(x, diag, out);
}

// Round 7
// 46.610 us; speedup vs baseline: 1.1391x; 1.0066x over previous
//
#include <hip/hip_runtime.h>

#define UNITS 4096
#define BATCH 8192

// out[b,j] = x[b,j] * w[j,j]  (masked_w = w * I collapses to a column scale).
//
// Structure (round 7): separate 16-block preamble compacts diag(w) into a
// 16 KB d_ws table (L1-resident in the hot kernel); hot kernel is straight-
// line, TWO float4s per thread (32 B), 16384 blocks — no loop, maximal TLP,
// halved block-scheduling overhead vs round 6's 32768 blocks.
// Round-6 result: 46.9 us total, main ~44 us = ~97% of the 6.29 TB/s mixed
// copy ceiling on 268 MB aggregate traffic.
typedef float vf4 __attribute__((ext_vector_type(4)));

constexpr int TPB   = 256;
constexpr int N4    = BATCH * UNITS / 4;      // 8,388,608 float4s
constexpr int VPT   = 2;                      // float4s per thread
constexpr int NBLK  = N4 / (TPB * VPT);       // 16384 blocks, exact
constexpr int CHUNK = TPB * VPT;              // 512 float4s per block (half row)

__global__ void extract_diag_kernel(const float* __restrict__ w,
                                    float* __restrict__ diag) {
    int j = blockIdx.x * blockDim.x + threadIdx.x;
    if (j < UNITS) {
        diag[j] = w[(size_t)j * (UNITS + 1)];
    }
}

__global__ void __launch_bounds__(TPB)
diag_scale_kernel(const float* __restrict__ x,
                  const float* __restrict__ diag,
                  float* __restrict__ out) {
    const vf4* __restrict__ x4 = (const vf4*)x;
    const vf4* __restrict__ d4 = (const vf4*)diag;
    vf4* __restrict__ o4 = (vf4*)out;

    // Two consecutive half-wavefront-strided elements: thread t handles
    // i and i + TPB within its block's 512-float4 chunk (both coalesced).
    const int base = blockIdx.x * CHUNK + threadIdx.x;
    const int i0 = base;
    const int i1 = base + TPB;
    const int c0 = i0 & (UNITS / 4 - 1);
    const int c1 = i1 & (UNITS / 4 - 1);

    vf4 dv0 = d4[c0];                         // 16 KB table: L1-hit
    vf4 dv1 = d4[c1];
    vf4 xv0 = x4[i0];                         // independent, both in flight
    vf4 xv1 = x4[i1];
    __builtin_nontemporal_store(xv0 * dv0, &o4[i0]);
    __builtin_nontemporal_store(xv1 * dv1, &o4[i1]);
}

extern "C" void kernel_launch(void* const* d_in, const int* in_sizes, int n_in,
                              void* d_out, int out_size, void* d_ws, size_t ws_size,
                              hipStream_t stream) {
    const float* x = (const float*)d_in[0];
    const float* w = (const float*)d_in[1];
    float* out = (float*)d_out;
    float* diag = (float*)d_ws;               // 16 KB scratch

    extract_diag_kernel<<<(UNITS + TPB - 1) / TPB, TPB, 0, stream>>>(w, diag);
    diag_scale_kernel<<<NBLK, TPB, 0, stream>>>(x, diag, out);
}